// Round 14
// baseline (126.016 us; speedup 1.0000x reference)
//
#include <hip/hip_runtime.h>

#define NB 8
#define NT 512
#define NS 512
#define NH 128
#define C2LOG2E 2.8853900817779268f   // 2*log2(e): exp2(C*x) = e^(2x)

typedef float v2f __attribute__((ext_vector_type(2)));

__device__ __forceinline__ float fast_exp2(float x) { return __builtin_amdgcn_exp2f(x); }
__device__ __forceinline__ float fast_rcp(float x)  { return __builtin_amdgcn_rcpf(x); }
__device__ __forceinline__ float fast_tanh(float x) {
  float e = fast_exp2(x * C2LOG2E);
  return 1.0f - 2.0f * fast_rcp(e + 1.0f);
}

__device__ __forceinline__ v2f vfma(v2f a, v2f b, v2f c) {
  return __builtin_elementwise_fma(a, b, c);
}
__device__ __forceinline__ v2f sp(float x) { v2f r = {x, x}; return r; }

// acc.c += sum_{i=0..7} v_i/(e_i*F_i.c+1): 8-term rational combine, ONE
// rcp per component per 8 h-terms. All math on 2-wide f32 vectors (the
// s-pair) -> backend selects v_pk_*_f32 dual-issue ops.
// den = product of 8 P's <= e^Sigma, Sigma ~ N(0,64): overflow needs 11
// sigma -> impossible.
__device__ __forceinline__ v2f oct_acc2(float4 ea, float4 eb,
                                        float4 va, float4 vb,
                                        v2f F0, v2f F1, v2f F2, v2f F3,
                                        v2f F4, v2f F5, v2f F6, v2f F7,
                                        v2f acc) {
  const v2f one = {1.f, 1.f};
  v2f P0 = vfma(sp(ea.x), F0, one);
  v2f P1 = vfma(sp(ea.y), F1, one);
  v2f P2 = vfma(sp(ea.z), F2, one);
  v2f P3 = vfma(sp(ea.w), F3, one);
  v2f P4 = vfma(sp(eb.x), F4, one);
  v2f P5 = vfma(sp(eb.y), F5, one);
  v2f P6 = vfma(sp(eb.z), F6, one);
  v2f P7 = vfma(sp(eb.w), F7, one);
  v2f d01 = P0 * P1, d23 = P2 * P3, d45 = P4 * P5, d67 = P6 * P7;
  v2f n01 = vfma(sp(va.x), P1, sp(va.y) * P0);
  v2f n23 = vfma(sp(va.z), P3, sp(va.w) * P2);
  v2f n45 = vfma(sp(vb.x), P5, sp(vb.y) * P4);
  v2f n67 = vfma(sp(vb.z), P7, sp(vb.w) * P6);
  v2f d03 = d01 * d23, d47 = d45 * d67;
  v2f n03 = vfma(n01, d23, n23 * d01);
  v2f n47 = vfma(n45, d67, n67 * d45);
  v2f den = d03 * d47;
  v2f num = vfma(n03, d47, n47 * d03);
  v2f rc = {fast_rcp(den.x), fast_rcp(den.y)};
  return vfma(num, rc, acc);
}

// ---------------- K1: four 4096x128x128 GEMMs ----------------
// set 0: EWS  = exp2(C*(q  @ W_s^T))            [b][t][h]
// set 1: EWHT = exp2(C*(enc@ W_h^T)) TRANSPOSED [b][h][s]
// set 2: ENCW = enc @ W1^T   (W1 = Wout[:, :128])        [b][s][c]
// set 3: QW2  = q @ W2^T + b (W2 = Wout[:, 128:])        [b][t][c]
// Register-blocked 4x4 per thread (64r x 64c per block, grid 512);
// K-loop in v2f packed f32 (r12). Also zeroes mega's work-queue counter
// (block 0 thread 0; stream order guarantees visibility before mega).
__global__ __launch_bounds__(256) void bah_proj_kernel(
    const float* __restrict__ query, const float* __restrict__ enc,
    const float* __restrict__ W_s, const float* __restrict__ W_h,
    const float* __restrict__ Wout, const float* __restrict__ Woutb,
    float* __restrict__ EWS, float* __restrict__ EWHT,
    float* __restrict__ ENCW, float* __restrict__ QW2,
    int* __restrict__ counter) {
  __shared__ __align__(16) float lds_w[64 * 132];   // 33 KB: one col-half
  __shared__ __align__(16) float lds_x[64 * 132];   // 33 KB; set1 reuse 64x68
  if (blockIdx.x == 0 && threadIdx.x == 0) counter[0] = 0;
  const int set = blockIdx.x >> 7;        // 128 blocks per set
  const int blk = blockIdx.x & 127;
  const int rb = blk >> 1, ch = blk & 1;  // rb 0..63
  const int r0 = rb * 64, c0 = ch * 64;
  const int tid = threadIdx.x;
  const float* in = (set == 1 || set == 2) ? enc : query;
  const float* Wb; int wst;
  if (set == 0)      { Wb = W_s;        wst = 128; }
  else if (set == 1) { Wb = W_h;        wst = 128; }
  else if (set == 2) { Wb = Wout;       wst = 256; }
  else               { Wb = Wout + 128; wst = 256; }
  for (int i = tid; i < 2048; i += 256) {           // W: 64 rows x 32 float4
    int r = i >> 5, c4 = i & 31;
    *(float4*)(lds_w + r * 132 + c4 * 4) =
        *(const float4*)(Wb + (c0 + r) * wst + c4 * 4);
  }
  for (int i = tid; i < 2048; i += 256) {           // x: 64 rows x 32 float4
    int r = i >> 5, c4 = i & 31;
    *(float4*)(lds_x + r * 132 + c4 * 4) =
        *(const float4*)(in + (r0 + r) * NH + c4 * 4);
  }
  __syncthreads();
  const int colg = tid & 15;       // cols c0 + colg + 16m, m=0..3
  const int rowg = tid >> 4;       // rows r0 + rowg*4 + i, i=0..3
  v2f accp[4][4];
  #pragma unroll
  for (int i = 0; i < 4; ++i)
    #pragma unroll
    for (int m = 0; m < 4; ++m) { accp[i][m].x = 0.f; accp[i][m].y = 0.f; }
  for (int k4 = 0; k4 < 32; ++k4) {
    v2f xa[4][2], wb[4][2];
    #pragma unroll
    for (int i = 0; i < 4; ++i) {    // 4 addrs/wave -> broadcast
      float4 t = *(const float4*)(lds_x + (rowg * 4 + i) * 132 + k4 * 4);
      xa[i][0].x = t.x; xa[i][0].y = t.y; xa[i][1].x = t.z; xa[i][1].y = t.w;
    }
    #pragma unroll
    for (int m = 0; m < 4; ++m) {    // bank 4(colg+k4)%32 -> 2-way (free)
      float4 t = *(const float4*)(lds_w + (colg + 16 * m) * 132 + k4 * 4);
      wb[m][0].x = t.x; wb[m][0].y = t.y; wb[m][1].x = t.z; wb[m][1].y = t.w;
    }
    #pragma unroll
    for (int i = 0; i < 4; ++i)
      #pragma unroll
      for (int m = 0; m < 4; ++m) {  // 2 pk-fma per output per k4
        accp[i][m] = vfma(xa[i][0], wb[m][0], accp[i][m]);
        accp[i][m] = vfma(xa[i][1], wb[m][1], accp[i][m]);
      }
  }
  float acc[4][4];
  #pragma unroll
  for (int i = 0; i < 4; ++i)
    #pragma unroll
    for (int m = 0; m < 4; ++m)
      acc[i][m] = accp[i][m].x + accp[i][m].y;
  if (set == 0) {
    #pragma unroll
    for (int i = 0; i < 4; ++i)
      #pragma unroll
      for (int m = 0; m < 4; ++m)    // lanes colg consecutive -> 64B segs
        EWS[(r0 + rowg * 4 + i) * NH + c0 + colg + 16 * m] =
            fast_exp2(C2LOG2E * acc[i][m]);
  } else if (set == 1) {
    __syncthreads();                 // lds_x dead; reuse as 64h x 68 transpose
    #pragma unroll
    for (int i = 0; i < 4; ++i)
      #pragma unroll
      for (int m = 0; m < 4; ++m)    // bank 4(colg+rowg)+i -> ~2-way
        lds_x[(colg + 16 * m) * 68 + rowg * 4 + i] =
            fast_exp2(C2LOG2E * acc[i][m]);
    __syncthreads();
    const int b = r0 >> 9, sl0 = r0 & 511;
    const int sc = tid & 15, hb = tid >> 4;   // 16 s-chunks x 16 h-rows
    #pragma unroll
    for (int g = 0; g < 4; ++g) {    // h = hb + 16g; lanes sc -> 256B segs
      int h = hb + 16 * g;
      *(float4*)(EWHT + b * NH * NS + (c0 + h) * NS + sl0 + sc * 4) =
          *(const float4*)(lds_x + h * 68 + sc * 4);
    }
  } else if (set == 2) {
    #pragma unroll
    for (int i = 0; i < 4; ++i)
      #pragma unroll
      for (int m = 0; m < 4; ++m)
        ENCW[(r0 + rowg * 4 + i) * NH + c0 + colg + 16 * m] = acc[i][m];
  } else {
    #pragma unroll
    for (int i = 0; i < 4; ++i)
      #pragma unroll
      for (int m = 0; m < 4; ++m) {
        int c = c0 + colg + 16 * m;  // bias folded here, not in mega
        QW2[(r0 + rowg * 4 + i) * NH + c] = acc[i][m] + Woutb[c];
      }
  }
}

// -------- K2: MEGA — scores + quirky softmax + attn x ENCW -> out ---------
// r12 phases inside a PERSISTENT-BLOCK work loop: grid 768 (3 blocks/CU,
// all resident), 1024 items (batch, 4 t-rows) grabbed via atomicAdd.
// Why: per-CU work is max over random batch lens (ceil(len/128) spans);
// static maps put batch 0 + random heavies on one CU (4x spread -> 27.8%
// occupancy tail). Dynamic grabbing balances to mean + one item. Items
// ordered batch-0-first (known len=512 -> heaviest, LPT order).
__global__ __launch_bounds__(256) void bah_mega_kernel(
    const float* __restrict__ EWS, const float* __restrict__ EWHT,
    const float* __restrict__ v, const float* __restrict__ ENCW,
    const float* __restrict__ QW2, const int* __restrict__ src_len,
    int* __restrict__ counter, float* __restrict__ out) {
  // Arena (floats): s_v[0,128) s_et[128,656) s_aT[656,2704)
  // s_sc[2704,4768) s_red[4768,4784). lred (phase D, 2048) overlays s_sc.
  __shared__ __align__(16) float smem[4784];
  __shared__ int s_item;
  float* s_v   = smem;
  float* s_et  = smem + 128;
  float* s_aT  = smem + 656;
  float* s_sc  = smem + 2704;
  float* s_red = smem + 4768;

  const int tid = threadIdx.x;
  if (tid < 32) *(float4*)(s_v + tid * 4) = *(const float4*)(v + tid * 4);
  __syncthreads();

  // V0 = sum(v) via one float2 read + wave shuffles (all lanes get it)
  float V0;
  {
    float2 vv = *(const float2*)(s_v + (tid & 63) * 2);
    V0 = vv.x + vv.y;
    #pragma unroll
    for (int msk = 1; msk <= 32; msk <<= 1)
      V0 += __shfl_xor(V0, msk, 64);
  }

  for (;;) {
    if (tid == 0) s_item = atomicAdd(counter, 1);
    __syncthreads();                      // also orders LDS reuse vs prev iter
    const int item = s_item;
    if (item >= 1024) break;
    const int bb = item >> 7;             // batch 0 first = heavy-first
    const int t0 = (item & 127) * 4;      // 4 t-rows per item
    const int len = src_len[bb];

    if (tid < 128) {                      // 4x128 EWS rows = 128 float4
      int r = tid >> 5, c4 = tid & 31;
      *(float4*)(s_et + r * 132 + c4 * 4) =
          *(const float4*)(EWS + (bb * NT + t0 + r) * NH + c4 * 4);
    }
    __syncthreads();

    // ---- Phase B: scores. Thread owns 2 contiguous s, ALL 128 h, 4 t.
    // Wave-level skip of fully-masked 128-s spans.
    const int sbase = tid * 2;
    v2f acc2[4];
    #pragma unroll
    for (int i = 0; i < 4; ++i) { acc2[i].x = 0.f; acc2[i].y = 0.f; }
    const int wave_s0 = (tid & ~63) * 2;  // wave-uniform start of 128-s span
    if (wave_s0 < len) {
      const float* fb = EWHT + bb * NH * NS + sbase;
      for (int ho = 0; ho < 16; ++ho) {   // 8 h-rows per iter
        const float* fh = fb + ho * 8 * NS;
        v2f F0 = *(const v2f*)(fh + 0 * NS);   // 512B/wave per row (L2)
        v2f F1 = *(const v2f*)(fh + 1 * NS);
        v2f F2 = *(const v2f*)(fh + 2 * NS);
        v2f F3 = *(const v2f*)(fh + 3 * NS);
        v2f F4 = *(const v2f*)(fh + 4 * NS);
        v2f F5 = *(const v2f*)(fh + 5 * NS);
        v2f F6 = *(const v2f*)(fh + 6 * NS);
        v2f F7 = *(const v2f*)(fh + 7 * NS);
        float4 va = *(const float4*)(s_v + ho * 8);      // block-uniform
        float4 vb = *(const float4*)(s_v + ho * 8 + 4);
        #pragma unroll
        for (int tt = 0; tt < 4; ++tt) {
          float4 e0 = *(const float4*)(s_et + tt * 132 + ho * 8);  // bcast
          float4 e1 = *(const float4*)(s_et + tt * 132 + ho * 8 + 4);
          acc2[tt] = oct_acc2(e0, e1, va, vb,
                              F0, F1, F2, F3, F4, F5, F6, F7, acc2[tt]);
        }
      }
    }
    #pragma unroll
    for (int tt = 0; tt < 4; ++tt) {      // no cross-thread reduce needed
      float2 r;  // faithful quirk: masked scores ZEROED, still in softmax
      r.x = (sbase + 0 < len) ? fmaf(-2.f, acc2[tt].x, V0) : 0.f;
      r.y = (sbase + 1 < len) ? fmaf(-2.f, acc2[tt].y, V0) : 0.f;
      *(float2*)(s_sc + tt * 516 + sbase) = r;  // contiguous 512B/wave
    }
    __syncthreads();

    // ---- Phase C: softmax per t-row (NO max-pass; scores bounded) ----
    const int t = tid & 3;
    const int c = tid >> 2;       // 0..63, 8 strided s values each
    const int wv = tid >> 6;
    float pv[8];
    float sum = 0.f;
    #pragma unroll
    for (int k = 0; k < 8; ++k) {
      pv[k] = fast_exp2(s_sc[t * 516 + c + 64 * k] * 1.4426950408889634f);
      sum += pv[k];
    }
    #pragma unroll
    for (int msk = 4; msk <= 32; msk <<= 1)
      sum += __shfl_xor(sum, msk, 64);
    if ((tid & 63) < 4) s_red[wv * 4 + t] = sum;
    __syncthreads();
    sum = 0.f;
    #pragma unroll
    for (int j = 0; j < 4; ++j) sum += s_red[j * 4 + t];
    const float rd = fast_rcp(sum);
    #pragma unroll
    for (int k = 0; k < 8; ++k)   // word 4(c+64k)+t: consecutive per wave
      s_aT[(c + 64 * k) * 4 + t] = pv[k] * rd;
    __syncthreads();

    // ---- Phase D': pre_out[t][c] = sum_s attn[t][s] * ENCW[s][c] ----
    // 8 s-groups x 64 s; one float4 attn read covers all 4 t-rows.
    const int hg = tid & 31, sg = tid >> 5;
    float4 a8[4] = {{0,0,0,0},{0,0,0,0},{0,0,0,0},{0,0,0,0}};
    const float* eb = ENCW + bb * NS * NH + hg * 4;
    for (int k = 0; k < 64; ++k) {
      int s = sg * 64 + k;
      float4 e = *(const float4*)(eb + s * NH);       // coalesced global
      float4 w = *(const float4*)(s_aT + s * 4);      // 2 addrs/wave: free
      a8[0].x += w.x*e.x; a8[0].y += w.x*e.y; a8[0].z += w.x*e.z; a8[0].w += w.x*e.w;
      a8[1].x += w.y*e.x; a8[1].y += w.y*e.y; a8[1].z += w.y*e.z; a8[1].w += w.y*e.w;
      a8[2].x += w.z*e.x; a8[2].y += w.z*e.y; a8[2].z += w.z*e.z; a8[2].w += w.z*e.w;
      a8[3].x += w.w*e.x; a8[3].y += w.w*e.y; a8[3].z += w.w*e.z; a8[3].w += w.w*e.w;
    }
    #pragma unroll
    for (int i = 0; i < 4; ++i) {     // sg pairs within wave (lane^32)
      a8[i].x += __shfl_xor(a8[i].x, 32, 64);
      a8[i].y += __shfl_xor(a8[i].y, 32, 64);
      a8[i].z += __shfl_xor(a8[i].z, 32, 64);
      a8[i].w += __shfl_xor(a8[i].w, 32, 64);
    }
    float* lred = s_sc;               // overlay (dead): needs 2048 <= 2064
    if ((tid & 63) < 32) {
      #pragma unroll
      for (int i = 0; i < 4; ++i)
        *(float4*)(lred + wv * 512 + i * 128 + hg * 4) = a8[i];
    }
    __syncthreads();
    {                                 // final reduce + QW2 (has bias) + tanh
      int tt = tid >> 6, h2 = tid & 63;
      float2 o = {0.f, 0.f};
      #pragma unroll
      for (int j = 0; j < 4; ++j) {
        float2 p = *(const float2*)(lred + j * 512 + tt * 128 + h2 * 2);
        o.x += p.x; o.y += p.y;
      }
      const int row = bb * NT + t0 + tt;
      float2 q2 = *(const float2*)(QW2 + row * NH + h2 * 2);  // coalesced
      float2 r;
      r.x = fast_tanh(o.x + q2.x);
      r.y = fast_tanh(o.y + q2.y);
      *(float2*)(out + row * NH + h2 * 2) = r;
    }
  }
}

extern "C" void kernel_launch(void* const* d_in, const int* in_sizes, int n_in,
                              void* d_out, int out_size, void* d_ws, size_t ws_size,
                              hipStream_t stream) {
  const float* query = (const float*)d_in[0];
  const float* enc   = (const float*)d_in[1];
  const int*   slen  = (const int*)d_in[2];
  const float* W_h   = (const float*)d_in[3];
  const float* W_s   = (const float*)d_in[4];
  const float* v     = (const float*)d_in[5];
  const float* Woutw = (const float*)d_in[6];
  const float* Woutb = (const float*)d_in[7];
  float* out = (float*)d_out;

  float* ws = (float*)d_ws;
  float* EWS  = ws;                  // B*T*H (2 MB)
  float* EWHT = ws + 524288;         // B*H*S transposed (2 MB)
  float* ENCW = ws + 1048576;        // B*S*H = enc @ W1^T (2 MB)
  float* QW2  = ws + 1572864;        // B*T*H = q @ W2^T + bias (2 MB)
  int*   cnt  = (int*)(ws + 2097152);  // work-queue counter (proj zeroes)

  bah_proj_kernel<<<512, 256, 0, stream>>>(query, enc, W_s, W_h, Woutw,
                                           Woutb, EWS, EWHT, ENCW, QW2, cnt);
  bah_mega_kernel<<<768, 256, 0, stream>>>(EWS, EWHT, v, ENCW, QW2, slen,
                                           cnt, out);
}

// Round 15
// 113.693 us; speedup vs baseline: 1.1084x; 1.1084x over previous
//
#include <hip/hip_runtime.h>

#define NB 8
#define NT 512
#define NS 512
#define NH 128
#define C2LOG2E 2.8853900817779268f   // 2*log2(e): exp2(C*x) = e^(2x)

typedef float v2f __attribute__((ext_vector_type(2)));

__device__ __forceinline__ float fast_exp2(float x) { return __builtin_amdgcn_exp2f(x); }
__device__ __forceinline__ float fast_rcp(float x)  { return __builtin_amdgcn_rcpf(x); }
__device__ __forceinline__ float fast_tanh(float x) {
  float e = fast_exp2(x * C2LOG2E);
  return 1.0f - 2.0f * fast_rcp(e + 1.0f);
}

__device__ __forceinline__ v2f vfma(v2f a, v2f b, v2f c) {
  return __builtin_elementwise_fma(a, b, c);
}
__device__ __forceinline__ v2f sp(float x) { v2f r = {x, x}; return r; }

// acc.c += sum_{i=0..7} v_i/(e_i*F_i.c+1): 8-term rational combine, ONE
// rcp per component per 8 h-terms. All math on 2-wide f32 vectors (the
// s-pair) -> backend selects v_pk_*_f32 dual-issue ops.
// den = product of 8 P's <= e^Sigma, Sigma ~ N(0,64): overflow needs 11
// sigma -> impossible.
__device__ __forceinline__ v2f oct_acc2(float4 ea, float4 eb,
                                        float4 va, float4 vb,
                                        v2f F0, v2f F1, v2f F2, v2f F3,
                                        v2f F4, v2f F5, v2f F6, v2f F7,
                                        v2f acc) {
  const v2f one = {1.f, 1.f};
  v2f P0 = vfma(sp(ea.x), F0, one);
  v2f P1 = vfma(sp(ea.y), F1, one);
  v2f P2 = vfma(sp(ea.z), F2, one);
  v2f P3 = vfma(sp(ea.w), F3, one);
  v2f P4 = vfma(sp(eb.x), F4, one);
  v2f P5 = vfma(sp(eb.y), F5, one);
  v2f P6 = vfma(sp(eb.z), F6, one);
  v2f P7 = vfma(sp(eb.w), F7, one);
  v2f d01 = P0 * P1, d23 = P2 * P3, d45 = P4 * P5, d67 = P6 * P7;
  v2f n01 = vfma(sp(va.x), P1, sp(va.y) * P0);
  v2f n23 = vfma(sp(va.z), P3, sp(va.w) * P2);
  v2f n45 = vfma(sp(vb.x), P5, sp(vb.y) * P4);
  v2f n67 = vfma(sp(vb.z), P7, sp(vb.w) * P6);
  v2f d03 = d01 * d23, d47 = d45 * d67;
  v2f n03 = vfma(n01, d23, n23 * d01);
  v2f n47 = vfma(n45, d67, n67 * d45);
  v2f den = d03 * d47;
  v2f num = vfma(n03, d47, n47 * d03);
  v2f rc = {fast_rcp(den.x), fast_rcp(den.y)};
  return vfma(num, rc, acc);
}

// ---------------- K1: four 4096x128x128 GEMMs ----------------
// set 0: EWS  = exp2(C*(q  @ W_s^T))            [b][t][h]
// set 1: EWHT = exp2(C*(enc@ W_h^T)) TRANSPOSED [b][h][s]
// set 2: ENCW = enc @ W1^T   (W1 = Wout[:, :128])        [b][s][c]
// set 3: QW2  = q @ W2^T + b (W2 = Wout[:, 128:])        [b][t][c]
// Register-blocked 4x4 per thread (64r x 64c per block, grid 512);
// K-loop in v2f packed f32 (r12, +1.2us).
__global__ __launch_bounds__(256) void bah_proj_kernel(
    const float* __restrict__ query, const float* __restrict__ enc,
    const float* __restrict__ W_s, const float* __restrict__ W_h,
    const float* __restrict__ Wout, const float* __restrict__ Woutb,
    float* __restrict__ EWS, float* __restrict__ EWHT,
    float* __restrict__ ENCW, float* __restrict__ QW2) {
  __shared__ __align__(16) float lds_w[64 * 132];   // 33 KB: one col-half
  __shared__ __align__(16) float lds_x[64 * 132];   // 33 KB; set1 reuse 64x68
  const int set = blockIdx.x >> 7;        // 128 blocks per set
  const int blk = blockIdx.x & 127;
  const int rb = blk >> 1, ch = blk & 1;  // rb 0..63
  const int r0 = rb * 64, c0 = ch * 64;
  const int tid = threadIdx.x;
  const float* in = (set == 1 || set == 2) ? enc : query;
  const float* Wb; int wst;
  if (set == 0)      { Wb = W_s;        wst = 128; }
  else if (set == 1) { Wb = W_h;        wst = 128; }
  else if (set == 2) { Wb = Wout;       wst = 256; }
  else               { Wb = Wout + 128; wst = 256; }
  for (int i = tid; i < 2048; i += 256) {           // W: 64 rows x 32 float4
    int r = i >> 5, c4 = i & 31;
    *(float4*)(lds_w + r * 132 + c4 * 4) =
        *(const float4*)(Wb + (c0 + r) * wst + c4 * 4);
  }
  for (int i = tid; i < 2048; i += 256) {           // x: 64 rows x 32 float4
    int r = i >> 5, c4 = i & 31;
    *(float4*)(lds_x + r * 132 + c4 * 4) =
        *(const float4*)(in + (r0 + r) * NH + c4 * 4);
  }
  __syncthreads();
  const int colg = tid & 15;       // cols c0 + colg + 16m, m=0..3
  const int rowg = tid >> 4;       // rows r0 + rowg*4 + i, i=0..3
  v2f accp[4][4];
  #pragma unroll
  for (int i = 0; i < 4; ++i)
    #pragma unroll
    for (int m = 0; m < 4; ++m) { accp[i][m].x = 0.f; accp[i][m].y = 0.f; }
  for (int k4 = 0; k4 < 32; ++k4) {
    v2f xa[4][2], wb[4][2];
    #pragma unroll
    for (int i = 0; i < 4; ++i) {    // 4 addrs/wave -> broadcast
      float4 t = *(const float4*)(lds_x + (rowg * 4 + i) * 132 + k4 * 4);
      xa[i][0].x = t.x; xa[i][0].y = t.y; xa[i][1].x = t.z; xa[i][1].y = t.w;
    }
    #pragma unroll
    for (int m = 0; m < 4; ++m) {    // bank 4(colg+k4)%32 -> 2-way (free)
      float4 t = *(const float4*)(lds_w + (colg + 16 * m) * 132 + k4 * 4);
      wb[m][0].x = t.x; wb[m][0].y = t.y; wb[m][1].x = t.z; wb[m][1].y = t.w;
    }
    #pragma unroll
    for (int i = 0; i < 4; ++i)
      #pragma unroll
      for (int m = 0; m < 4; ++m) {  // 2 pk-fma per output per k4
        accp[i][m] = vfma(xa[i][0], wb[m][0], accp[i][m]);
        accp[i][m] = vfma(xa[i][1], wb[m][1], accp[i][m]);
      }
  }
  float acc[4][4];
  #pragma unroll
  for (int i = 0; i < 4; ++i)
    #pragma unroll
    for (int m = 0; m < 4; ++m)
      acc[i][m] = accp[i][m].x + accp[i][m].y;
  if (set == 0) {
    #pragma unroll
    for (int i = 0; i < 4; ++i)
      #pragma unroll
      for (int m = 0; m < 4; ++m)    // lanes colg consecutive -> 64B segs
        EWS[(r0 + rowg * 4 + i) * NH + c0 + colg + 16 * m] =
            fast_exp2(C2LOG2E * acc[i][m]);
  } else if (set == 1) {
    __syncthreads();                 // lds_x dead; reuse as 64h x 68 transpose
    #pragma unroll
    for (int i = 0; i < 4; ++i)
      #pragma unroll
      for (int m = 0; m < 4; ++m)    // bank 4(colg+rowg)+i -> ~2-way
        lds_x[(colg + 16 * m) * 68 + rowg * 4 + i] =
            fast_exp2(C2LOG2E * acc[i][m]);
    __syncthreads();
    const int b = r0 >> 9, sl0 = r0 & 511;
    const int sc = tid & 15, hb = tid >> 4;   // 16 s-chunks x 16 h-rows
    #pragma unroll
    for (int g = 0; g < 4; ++g) {    // h = hb + 16g; lanes sc -> 256B segs
      int h = hb + 16 * g;
      *(float4*)(EWHT + b * NH * NS + (c0 + h) * NS + sl0 + sc * 4) =
          *(const float4*)(lds_x + h * 68 + sc * 4);
    }
  } else if (set == 2) {
    #pragma unroll
    for (int i = 0; i < 4; ++i)
      #pragma unroll
      for (int m = 0; m < 4; ++m)
        ENCW[(r0 + rowg * 4 + i) * NH + c0 + colg + 16 * m] = acc[i][m];
  } else {
    #pragma unroll
    for (int i = 0; i < 4; ++i)
      #pragma unroll
      for (int m = 0; m < 4; ++m) {
        int c = c0 + colg + 16 * m;  // bias folded here, not in mega
        QW2[(r0 + rowg * 4 + i) * NH + c] = acc[i][m] + Woutb[c];
      }
  }
}

// -------- K2: MEGA — scores + quirky softmax + attn x ENCW -> out ---------
// r12 verbatim (best measured: 114.0 total): 256 threads, 4 t-rows/block,
// grid 1024, f32 streams, oct_acc2 packed combine, softmax without
// max-pass, scalar phase D (r13's packed D was null, r14's persistent
// work-loop regressed -12us: fewer resident waves + serialized items).
__global__ __launch_bounds__(256) void bah_mega_kernel(
    const float* __restrict__ EWS, const float* __restrict__ EWHT,
    const float* __restrict__ v, const float* __restrict__ ENCW,
    const float* __restrict__ QW2, const int* __restrict__ src_len,
    float* __restrict__ out) {
  // Arena (floats): s_v[0,128) s_et[128,656) s_aT[656,2704)
  // s_sc[2704,4768) s_red[4768,4784). lred (phase D, 2048) overlays s_sc.
  __shared__ __align__(16) float smem[4784];
  float* s_v   = smem;
  float* s_et  = smem + 128;
  float* s_aT  = smem + 656;
  float* s_sc  = smem + 2704;
  float* s_red = smem + 4768;

  const int tid = threadIdx.x;
  const int bb = blockIdx.x >> 7;         // batch-major; %8 dispatch balances
  const int t0 = (blockIdx.x & 127) * 4;  // 4 t-rows per block
  const int len = src_len[bb];

  if (tid < 32) *(float4*)(s_v + tid * 4) = *(const float4*)(v + tid * 4);
  if (tid < 128) {                     // 4x128 EWS rows = 128 float4
    int r = tid >> 5, c4 = tid & 31;
    *(float4*)(s_et + r * 132 + c4 * 4) =
        *(const float4*)(EWS + (bb * NT + t0 + r) * NH + c4 * 4);
  }
  __syncthreads();

  // V0 = sum(v) via one float2 read + wave shuffles (all lanes get it)
  float V0;
  {
    float2 vv = *(const float2*)(s_v + (tid & 63) * 2);
    V0 = vv.x + vv.y;
    #pragma unroll
    for (int msk = 1; msk <= 32; msk <<= 1)
      V0 += __shfl_xor(V0, msk, 64);
  }

  // ---- Phase B: scores. Thread owns 2 contiguous s, ALL 128 h, 4 t.
  // Wave-level skip of fully-masked 128-s spans.
  const int sbase = tid * 2;
  v2f acc2[4];
  #pragma unroll
  for (int i = 0; i < 4; ++i) { acc2[i].x = 0.f; acc2[i].y = 0.f; }
  const int wave_s0 = (tid & ~63) * 2;    // wave-uniform start of 128-s span
  if (wave_s0 < len) {
    const float* fb = EWHT + bb * NH * NS + sbase;
    for (int ho = 0; ho < 16; ++ho) {     // 8 h-rows per iter
      const float* fh = fb + ho * 8 * NS;
      v2f F0 = *(const v2f*)(fh + 0 * NS);   // 512B/wave per row (L2)
      v2f F1 = *(const v2f*)(fh + 1 * NS);
      v2f F2 = *(const v2f*)(fh + 2 * NS);
      v2f F3 = *(const v2f*)(fh + 3 * NS);
      v2f F4 = *(const v2f*)(fh + 4 * NS);
      v2f F5 = *(const v2f*)(fh + 5 * NS);
      v2f F6 = *(const v2f*)(fh + 6 * NS);
      v2f F7 = *(const v2f*)(fh + 7 * NS);
      float4 va = *(const float4*)(s_v + ho * 8);      // block-uniform
      float4 vb = *(const float4*)(s_v + ho * 8 + 4);
      #pragma unroll
      for (int tt = 0; tt < 4; ++tt) {
        float4 e0 = *(const float4*)(s_et + tt * 132 + ho * 8);  // bcast
        float4 e1 = *(const float4*)(s_et + tt * 132 + ho * 8 + 4);
        acc2[tt] = oct_acc2(e0, e1, va, vb,
                            F0, F1, F2, F3, F4, F5, F6, F7, acc2[tt]);
      }
    }
  }
  #pragma unroll
  for (int tt = 0; tt < 4; ++tt) {       // no cross-thread reduce needed
    float2 r;  // faithful quirk: masked scores ZEROED, still in softmax
    r.x = (sbase + 0 < len) ? fmaf(-2.f, acc2[tt].x, V0) : 0.f;
    r.y = (sbase + 1 < len) ? fmaf(-2.f, acc2[tt].y, V0) : 0.f;
    *(float2*)(s_sc + tt * 516 + sbase) = r;  // contiguous 512B/wave
  }
  __syncthreads();

  // ---- Phase C: softmax per t-row (NO max-pass; scores bounded) ----
  const int t = tid & 3;
  const int c = tid >> 2;       // 0..63, 8 strided s values each
  const int wv = tid >> 6;
  float pv[8];
  float sum = 0.f;
  #pragma unroll
  for (int k = 0; k < 8; ++k) {
    pv[k] = fast_exp2(s_sc[t * 516 + c + 64 * k] * 1.4426950408889634f);
    sum += pv[k];
  }
  #pragma unroll
  for (int msk = 4; msk <= 32; msk <<= 1)
    sum += __shfl_xor(sum, msk, 64);
  if ((tid & 63) < 4) s_red[wv * 4 + t] = sum;
  __syncthreads();
  sum = 0.f;
  #pragma unroll
  for (int j = 0; j < 4; ++j) sum += s_red[j * 4 + t];
  const float rd = fast_rcp(sum);
  #pragma unroll
  for (int k = 0; k < 8; ++k)   // word 4(c+64k)+t: consecutive per wave
    s_aT[(c + 64 * k) * 4 + t] = pv[k] * rd;
  __syncthreads();

  // ---- Phase D': pre_out[t][c] = sum_s attn[t][s] * ENCW[s][c] ----
  // 8 s-groups x 64 s; one float4 attn read covers all 4 t-rows.
  const int hg = tid & 31, sg = tid >> 5;
  float4 a8[4] = {{0,0,0,0},{0,0,0,0},{0,0,0,0},{0,0,0,0}};
  const float* eb = ENCW + bb * NS * NH + hg * 4;
  for (int k = 0; k < 64; ++k) {
    int s = sg * 64 + k;
    float4 e = *(const float4*)(eb + s * NH);       // coalesced global
    float4 w = *(const float4*)(s_aT + s * 4);      // 2 addrs/wave: free
    a8[0].x += w.x*e.x; a8[0].y += w.x*e.y; a8[0].z += w.x*e.z; a8[0].w += w.x*e.w;
    a8[1].x += w.y*e.x; a8[1].y += w.y*e.y; a8[1].z += w.y*e.z; a8[1].w += w.y*e.w;
    a8[2].x += w.z*e.x; a8[2].y += w.z*e.y; a8[2].z += w.z*e.z; a8[2].w += w.z*e.w;
    a8[3].x += w.w*e.x; a8[3].y += w.w*e.y; a8[3].z += w.w*e.z; a8[3].w += w.w*e.w;
  }
  #pragma unroll
  for (int i = 0; i < 4; ++i) {     // sg pairs within wave (lane^32)
    a8[i].x += __shfl_xor(a8[i].x, 32, 64);
    a8[i].y += __shfl_xor(a8[i].y, 32, 64);
    a8[i].z += __shfl_xor(a8[i].z, 32, 64);
    a8[i].w += __shfl_xor(a8[i].w, 32, 64);
  }
  float* lred = s_sc;               // overlay (dead): needs 2048 <= 2064
  if ((tid & 63) < 32) {
    #pragma unroll
    for (int i = 0; i < 4; ++i)
      *(float4*)(lred + wv * 512 + i * 128 + hg * 4) = a8[i];
  }
  __syncthreads();
  {                                 // final reduce + QW2 (has bias) + tanh
    int tt = tid >> 6, h2 = tid & 63;
    float2 o = {0.f, 0.f};
    #pragma unroll
    for (int j = 0; j < 4; ++j) {
      float2 p = *(const float2*)(lred + j * 512 + tt * 128 + h2 * 2);
      o.x += p.x; o.y += p.y;
    }
    const int row = bb * NT + t0 + tt;
    float2 q2 = *(const float2*)(QW2 + row * NH + h2 * 2);  // coalesced
    float2 r;
    r.x = fast_tanh(o.x + q2.x);
    r.y = fast_tanh(o.y + q2.y);
    *(float2*)(out + row * NH + h2 * 2) = r;
  }
}

extern "C" void kernel_launch(void* const* d_in, const int* in_sizes, int n_in,
                              void* d_out, int out_size, void* d_ws, size_t ws_size,
                              hipStream_t stream) {
  const float* query = (const float*)d_in[0];
  const float* enc   = (const float*)d_in[1];
  const int*   slen  = (const int*)d_in[2];
  const float* W_h   = (const float*)d_in[3];
  const float* W_s   = (const float*)d_in[4];
  const float* v     = (const float*)d_in[5];
  const float* Woutw = (const float*)d_in[6];
  const float* Woutb = (const float*)d_in[7];
  float* out = (float*)d_out;

  float* ws = (float*)d_ws;
  float* EWS  = ws;                  // B*T*H (2 MB)
  float* EWHT = ws + 524288;         // B*H*S transposed (2 MB)
  float* ENCW = ws + 1048576;        // B*S*H = enc @ W1^T (2 MB)
  float* QW2  = ws + 1572864;        // B*T*H = q @ W2^T + bias (2 MB)

  bah_proj_kernel<<<512, 256, 0, stream>>>(query, enc, W_s, W_h, Woutw,
                                           Woutb, EWS, EWHT, ENCW, QW2);
  bah_mega_kernel<<<1024, 256, 0, stream>>>(EWS, EWHT, v, ENCW, QW2, slen, out);
}